// Round 1
// baseline (468.457 us; speedup 1.0000x reference)
//
#include <hip/hip_runtime.h>
#include <hip/hip_bf16.h>
#include <math.h>

#define NB 1024
#define NC 100000
#define ND 512
#define SSCALE 64.0f
#define MMARGIN 0.5f

typedef __bf16 bf16x8 __attribute__((ext_vector_type(8)));
typedef float f32x4 __attribute__((ext_vector_type(4)));

// ---------------------------------------------------------------------------
// ws layout:
//   [0, 1MB)            : xnb  bf16[NB][ND]   (L2-normalized x, bf16)
//   [1MB, 1MB+4KB)      : sums float[NB]      (sum_c exp(s*wf[b,c]))
//   [1MB+4KB, 1MB+8KB)  : tgt  float[NB]      (wf[b, label_b], fp32)
// ---------------------------------------------------------------------------

// One block (256 thr) per row: compute 1/||x||, write bf16 normalized row.
__global__ void prep_kernel(const float* __restrict__ x, __bf16* __restrict__ xnb) {
    const int row = blockIdx.x;
    const int tid = threadIdx.x;
    const float2 v = *reinterpret_cast<const float2*>(x + (size_t)row * ND + tid * 2);
    float ss = v.x * v.x + v.y * v.y;
#pragma unroll
    for (int m = 1; m < 64; m <<= 1) ss += __shfl_xor(ss, m);
    __shared__ float wsum[4];
    if ((tid & 63) == 0) wsum[tid >> 6] = ss;
    __syncthreads();
    const float tot = wsum[0] + wsum[1] + wsum[2] + wsum[3];
    const float inv = 1.0f / fmaxf(sqrtf(tot), 1e-12f);
    __bf16* dst = xnb + (size_t)row * ND + tid * 2;
    dst[0] = (__bf16)(v.x * inv);
    dst[1] = (__bf16)(v.y * inv);
}

// One wave per row: tgt[b] = dot(xn_b, W[label_b])  (fp32 accumulate)
__global__ void target_kernel(const __bf16* __restrict__ xnb, const float* __restrict__ Wg,
                              const int* __restrict__ labels, float* __restrict__ tgt) {
    const int wid  = threadIdx.x >> 6;
    const int lane = threadIdx.x & 63;
    const int row  = blockIdx.x * 4 + wid;
    const int lab  = labels[row];
    const int k    = lane * 8;
    const bf16x8 xv = *reinterpret_cast<const bf16x8*>(xnb + (size_t)row * ND + k);
    const float* wr = Wg + (size_t)lab * ND + k;
    const float4 w0 = *reinterpret_cast<const float4*>(wr);
    const float4 w1 = *reinterpret_cast<const float4*>(wr + 4);
    float s = (float)xv[0] * w0.x + (float)xv[1] * w0.y + (float)xv[2] * w0.z + (float)xv[3] * w0.w
            + (float)xv[4] * w1.x + (float)xv[5] * w1.y + (float)xv[6] * w1.z + (float)xv[7] * w1.w;
#pragma unroll
    for (int m = 1; m < 64; m <<= 1) s += __shfl_xor(s, m);
    if (lane == 0) tgt[row] = s;
}

// Block = 256 thr (4 waves), c-tile of 64 classes, full K=512 staged in LDS.
// Each block sweeps ALL 1024 rows (4 chunks x 256 rows; wave = 64 rows).
// Epilogue fuses exp(s*logit) + row-sum; atomicAdd into sums[b].
__global__ __launch_bounds__(256, 2) void gemm_exp_kernel(const __bf16* __restrict__ xnb,
                                                          const float* __restrict__ Wg,
                                                          float* __restrict__ sums) {
    __shared__ char wtile[64 * 512 * 2];  // 64KB, swizzled bf16 [cls][k]
    const int tid = threadIdx.x;
    const int c0  = blockIdx.x * 64;

    // ---- stage W tile (fp32 -> bf16), coalesced float4 reads ----
#pragma unroll
    for (int it = 0; it < 32; ++it) {
        const int f   = it * 256 + tid;   // float4 index within tile, 0..8191
        const int cls = f >> 7;           // 128 float4 per class row
        const int k4  = f & 127;
        float4 v = make_float4(0.f, 0.f, 0.f, 0.f);
        if (c0 + cls < NC)
            v = *reinterpret_cast<const float4*>(Wg + (size_t)(c0 + cls) * ND + k4 * 4);
        struct alignas(8) bf4 { __bf16 a, b, c, d; };
        bf4 h{ (__bf16)v.x, (__bf16)v.y, (__bf16)v.z, (__bf16)v.w };
        int byte = cls * 1024 + k4 * 8;
        byte ^= (cls & 7) << 4;           // XOR swizzle (same on read)
        *reinterpret_cast<bf4*>(wtile + byte) = h;
    }
    __syncthreads();

    const int wid  = tid >> 6;
    const int lane = tid & 63;
    const int l15  = lane & 15;
    const int lhi  = lane >> 4;

    for (int ch = 0; ch < 4; ++ch) {
        const int rbase = ch * 256 + wid * 64;
        f32x4 acc[4][4] = {};
#pragma unroll 1
        for (int kk = 0; kk < 16; ++kk) {
            const int k = kk * 32 + lhi * 8;
            bf16x8 a[4], b[4];
#pragma unroll
            for (int i = 0; i < 4; ++i) {
                const int row = rbase + i * 16 + l15;
                a[i] = *reinterpret_cast<const bf16x8*>(xnb + (size_t)row * ND + k);
            }
#pragma unroll
            for (int j = 0; j < 4; ++j) {
                const int cls = j * 16 + l15;
                int byte = cls * 1024 + k * 2;
                byte ^= (cls & 7) << 4;
                b[j] = *reinterpret_cast<const bf16x8*>(wtile + byte);
            }
#pragma unroll
            for (int i = 0; i < 4; ++i)
#pragma unroll
                for (int j = 0; j < 4; ++j)
                    acc[i][j] = __builtin_amdgcn_mfma_f32_16x16x32_bf16(a[i], b[j], acc[i][j], 0, 0, 0);
        }
        // ---- epilogue: exp + row-sum reduce + atomic accumulate ----
#pragma unroll
        for (int i = 0; i < 4; ++i) {
#pragma unroll
            for (int r = 0; r < 4; ++r) {
                float v = 0.f;
#pragma unroll
                for (int j = 0; j < 4; ++j) {
                    const int c = c0 + j * 16 + l15;
                    v += (c < NC) ? __expf(SSCALE * acc[i][j][r]) : 0.f;
                }
                v += __shfl_xor(v, 1);
                v += __shfl_xor(v, 2);
                v += __shfl_xor(v, 4);
                v += __shfl_xor(v, 8);
                if (l15 == 0) {
                    const int row = rbase + i * 16 + lhi * 4 + r;
                    atomicAdd(&sums[row], v);
                }
            }
        }
    }
}

// Single block, 1024 threads: arcface formula per row + mean.
__global__ void finalize_kernel(const float* __restrict__ sums, const float* __restrict__ tgt,
                                float* __restrict__ out) {
    const int tid  = threadIdx.x;
    const int wid  = tid >> 6;
    const int lane = tid & 63;
    float t  = tgt[tid];
    const float se = sums[tid];
    t = fminf(fmaxf(t, -1.0f + 1e-7f), 1.0f - 1e-7f);
    const float numer = SSCALE * cosf(acosf(t) + MMARGIN);
    const float excl  = se - expf(SSCALE * t);
    float L = numer - logf(expf(numer) + excl);
#pragma unroll
    for (int m = 1; m < 64; m <<= 1) L += __shfl_xor(L, m);
    __shared__ float ws2[16];
    if (lane == 0) ws2[wid] = L;
    __syncthreads();
    if (tid == 0) {
        float tot = 0.f;
        for (int i = 0; i < 16; ++i) tot += ws2[i];
        out[0] = -(tot / (float)NB);
    }
}

extern "C" void kernel_launch(void* const* d_in, const int* in_sizes, int n_in,
                              void* d_out, int out_size, void* d_ws, size_t ws_size,
                              hipStream_t stream) {
    const float* x      = (const float*)d_in[0];
    const int*   labels = (const int*)d_in[1];
    const float* W      = (const float*)d_in[2];
    float* out = (float*)d_out;

    char* wsb = (char*)d_ws;
    __bf16* xnb  = (__bf16*)wsb;
    float*  sums = (float*)(wsb + (size_t)NB * ND * 2);
    float*  tgt  = sums + NB;

    hipMemsetAsync(sums, 0, NB * sizeof(float), stream);
    prep_kernel<<<NB, 256, 0, stream>>>(x, xnb);
    target_kernel<<<NB / 4, 256, 0, stream>>>(xnb, W, labels, tgt);
    gemm_exp_kernel<<<(NC + 63) / 64, 256, 0, stream>>>(xnb, W, sums);
    finalize_kernel<<<1, 1024, 0, stream>>>(sums, tgt, out);
}

// Round 2
// 194.082 us; speedup vs baseline: 2.4137x; 2.4137x over previous
//
#include <hip/hip_runtime.h>
#include <hip/hip_bf16.h>
#include <math.h>

#define NB 1024
#define NC 100000
#define ND 512
#define SSCALE 64.0f
#define MMARGIN 0.5f

#define BM 128
#define BN 128
#define BK 64
#define NKS (ND / BK)               // 8 K-steps
#define NRT (NB / BM)               // 8 row tiles
#define NCT ((NC + BN - 1) / BN)    // 782 col tiles
#define GRIDSZ (NRT * NCT)          // 6256 = 8 * 782 (exact -> bijective swizzle)

typedef __bf16 bf16x8 __attribute__((ext_vector_type(8)));
typedef float f32x4 __attribute__((ext_vector_type(4)));

__device__ __forceinline__ void gload_lds16(const void* g, void* l) {
    __builtin_amdgcn_global_load_lds(
        (const __attribute__((address_space(1))) unsigned int*)g,
        (__attribute__((address_space(3))) unsigned int*)l, 16, 0, 0);
}

// ---------------------------------------------------------------------------
// ws layout: [0,1MB) xnb bf16[NB][ND] ; then sums float[NB] ; tgt float[NB]
// ---------------------------------------------------------------------------

__global__ void prep_kernel(const float* __restrict__ x, __bf16* __restrict__ xnb) {
    const int row = blockIdx.x;
    const int tid = threadIdx.x;
    const float2 v = *reinterpret_cast<const float2*>(x + (size_t)row * ND + tid * 2);
    float ss = v.x * v.x + v.y * v.y;
#pragma unroll
    for (int m = 1; m < 64; m <<= 1) ss += __shfl_xor(ss, m);
    __shared__ float wsum[4];
    if ((tid & 63) == 0) wsum[tid >> 6] = ss;
    __syncthreads();
    const float tot = wsum[0] + wsum[1] + wsum[2] + wsum[3];
    const float inv = 1.0f / fmaxf(sqrtf(tot), 1e-12f);
    __bf16* dst = xnb + (size_t)row * ND + tid * 2;
    dst[0] = (__bf16)(v.x * inv);
    dst[1] = (__bf16)(v.y * inv);
}

__global__ void target_kernel(const __bf16* __restrict__ xnb, const float* __restrict__ Wg,
                              const int* __restrict__ labels, float* __restrict__ tgt) {
    const int wid  = threadIdx.x >> 6;
    const int lane = threadIdx.x & 63;
    const int row  = blockIdx.x * 4 + wid;
    const int lab  = labels[row];
    const int k    = lane * 8;
    const bf16x8 xv = *reinterpret_cast<const bf16x8*>(xnb + (size_t)row * ND + k);
    const float* wr = Wg + (size_t)lab * ND + k;
    const float4 w0 = *reinterpret_cast<const float4*>(wr);
    const float4 w1 = *reinterpret_cast<const float4*>(wr + 4);
    float s = (float)xv[0] * w0.x + (float)xv[1] * w0.y + (float)xv[2] * w0.z + (float)xv[3] * w0.w
            + (float)xv[4] * w1.x + (float)xv[5] * w1.y + (float)xv[6] * w1.z + (float)xv[7] * w1.w;
#pragma unroll
    for (int m = 1; m < 64; m <<= 1) s += __shfl_xor(s, m);
    if (lane == 0) tgt[row] = s;
}

// 128x128x64 double-buffered-A / single-buffered-B GEMM with fused exp+rowsum.
// A = xnb (bf16) via global_load_lds w16, pre-swizzled source (rule 21).
// B = W (fp32) reg-staged (T14), converted to bf16, XOR-swizzled ds_write.
// LDS: A 2x16KB @0, B 16KB @32768 -> 48KB -> 3 blocks/CU.
__global__ __launch_bounds__(256, 3) void gemm_exp_kernel(const __bf16* __restrict__ xnb,
                                                          const float* __restrict__ Wg,
                                                          float* __restrict__ sums) {
    __shared__ char lds[49152];
    const int tid  = threadIdx.x;
    const int wid  = tid >> 6;
    const int lane = tid & 63;
    const int l15  = lane & 15;
    const int lhi  = lane >> 4;
    const int wr   = wid >> 1;
    const int wc   = wid & 1;

    // XCD-chunked bijective swizzle: default xcd = bid%8 gets contiguous logical
    // chunk; within chunk row-tile is fastest -> 8 blocks sharing a B-panel run
    // back-to-back on one XCD (panel stays in its 4MB L2).
    const int logical = (blockIdx.x & 7) * (GRIDSZ / 8) + (blockIdx.x >> 3);
    const int rt = logical & 7;
    const int ct = logical >> 3;
    const int r0 = rt * BM;
    const int c0 = ct * BN;

    float4 bw[8];  // staged B regs: 4 x (2 float4) = one 16B bf16 chunk each pair

    const int bcls = (tid >> 3);        // 0..31, + l*32
    const int bqp  = tid & 7;           // float4-pair index within 64-float window

    // ---- B: issue 8 coalesced float4 loads for K-step t ----
    auto loadB = [&](int t) {
#pragma unroll
        for (int l = 0; l < 4; ++l) {
            const int cls = l * 32 + bcls;
            const float* src = Wg + (size_t)(c0 + cls) * ND + t * BK + bqp * 8;
            if (c0 + cls < NC) {
                bw[l * 2]     = *reinterpret_cast<const float4*>(src);
                bw[l * 2 + 1] = *reinterpret_cast<const float4*>(src + 4);
            } else {
                bw[l * 2]     = make_float4(0.f, 0.f, 0.f, 0.f);
                bw[l * 2 + 1] = make_float4(0.f, 0.f, 0.f, 0.f);
            }
        }
    };
    // ---- B: cvt + swizzled ds_write_b128 ----
    auto writeB = [&]() {
#pragma unroll
        for (int l = 0; l < 4; ++l) {
            const int cls = l * 32 + bcls;
            struct alignas(16) bf8s { __bf16 h[8]; };
            bf8s h;
            const float4 v0 = bw[l * 2], v1 = bw[l * 2 + 1];
            h.h[0] = (__bf16)v0.x; h.h[1] = (__bf16)v0.y; h.h[2] = (__bf16)v0.z; h.h[3] = (__bf16)v0.w;
            h.h[4] = (__bf16)v1.x; h.h[5] = (__bf16)v1.y; h.h[6] = (__bf16)v1.z; h.h[7] = (__bf16)v1.w;
            const int byte = 32768 + cls * 128 + ((bqp ^ (cls & 7)) << 4);
            *reinterpret_cast<bf8s*>(lds + byte) = h;
        }
    };
    // ---- A: async global->LDS, source pre-swizzled so linear dest == swizzled tile ----
    auto stageA = [&](int t, int buf) {
#pragma unroll
        for (int it = 0; it < 4; ++it) {
            const int row = it * 32 + wid * 8 + (lane >> 3);
            const int c   = lane & 7;
            const int lc  = c ^ (row & 7);
            const char* src = (const char*)xnb + (size_t)(r0 + row) * (ND * 2) + t * (BK * 2) + lc * 16;
            char* dstbase = lds + buf * 16384 + it * 4096 + wid * 1024;  // wave-uniform
            gload_lds16(src, dstbase);
        }
    };

    f32x4 acc[4][4] = {};

    auto compute = [&](int buf) {
#pragma unroll
        for (int kk = 0; kk < 2; ++kk) {
            bf16x8 a[4], b[4];
#pragma unroll
            for (int i = 0; i < 4; ++i) {
                const int r = wr * 64 + i * 16 + l15;
                const int byte = buf * 16384 + r * 128 + ((((kk << 2) | lhi) ^ (r & 7)) << 4);
                a[i] = *reinterpret_cast<const bf16x8*>(lds + byte);
            }
#pragma unroll
            for (int j = 0; j < 4; ++j) {
                const int cc = wc * 64 + j * 16 + l15;
                const int byte = 32768 + cc * 128 + ((((kk << 2) | lhi) ^ (cc & 7)) << 4);
                b[j] = *reinterpret_cast<const bf16x8*>(lds + byte);
            }
#pragma unroll
            for (int i = 0; i < 4; ++i)
#pragma unroll
                for (int j = 0; j < 4; ++j)
                    acc[i][j] = __builtin_amdgcn_mfma_f32_16x16x32_bf16(a[i], b[j], acc[i][j], 0, 0, 0);
        }
    };

    // ---- prologue: stage step 0 ----
    loadB(0);
    stageA(0, 0);
    writeB();           // compiler waits the bw loads
    __syncthreads();    // drains gload_lds vmcnt too
    int cur = 0;
#pragma unroll 1
    for (int t = 0; t < NKS; ++t) {
        if (t + 1 < NKS) {
            loadB(t + 1);           // issue early (latency hides under MFMA)
            stageA(t + 1, cur ^ 1); // async into other A buffer
        }
        compute(cur);
        __syncthreads();            // all B reads done + A(t+1) landed (vmcnt drained)
        if (t + 1 < NKS) writeB();
        __syncthreads();
        cur ^= 1;
    }

    // ---- epilogue: exp + row-sum + atomic ----
#pragma unroll
    for (int i = 0; i < 4; ++i) {
#pragma unroll
        for (int r = 0; r < 4; ++r) {
            float v = 0.f;
#pragma unroll
            for (int j = 0; j < 4; ++j) {
                const int c = c0 + wc * 64 + j * 16 + l15;
                v += (c < NC) ? __expf(SSCALE * acc[i][j][r]) : 0.f;
            }
            v += __shfl_xor(v, 1);
            v += __shfl_xor(v, 2);
            v += __shfl_xor(v, 4);
            v += __shfl_xor(v, 8);
            if (l15 == 0) {
                const int row = r0 + wr * 64 + i * 16 + lhi * 4 + r;
                atomicAdd(&sums[row], v);
            }
        }
    }
}

__global__ void finalize_kernel(const float* __restrict__ sums, const float* __restrict__ tgt,
                                float* __restrict__ out) {
    const int tid  = threadIdx.x;
    const int wid  = tid >> 6;
    const int lane = tid & 63;
    float t  = tgt[tid];
    const float se = sums[tid];
    t = fminf(fmaxf(t, -1.0f + 1e-7f), 1.0f - 1e-7f);
    const float numer = SSCALE * cosf(acosf(t) + MMARGIN);
    const float excl  = se - expf(SSCALE * t);
    float L = numer - logf(expf(numer) + excl);
#pragma unroll
    for (int m = 1; m < 64; m <<= 1) L += __shfl_xor(L, m);
    __shared__ float ws2[16];
    if (lane == 0) ws2[wid] = L;
    __syncthreads();
    if (tid == 0) {
        float tot = 0.f;
        for (int i = 0; i < 16; ++i) tot += ws2[i];
        out[0] = -(tot / (float)NB);
    }
}

extern "C" void kernel_launch(void* const* d_in, const int* in_sizes, int n_in,
                              void* d_out, int out_size, void* d_ws, size_t ws_size,
                              hipStream_t stream) {
    const float* x      = (const float*)d_in[0];
    const int*   labels = (const int*)d_in[1];
    const float* W      = (const float*)d_in[2];
    float* out = (float*)d_out;

    char* wsb = (char*)d_ws;
    __bf16* xnb  = (__bf16*)wsb;
    float*  sums = (float*)(wsb + (size_t)NB * ND * 2);
    float*  tgt  = sums + NB;

    hipMemsetAsync(sums, 0, NB * sizeof(float), stream);
    prep_kernel<<<NB, 256, 0, stream>>>(x, xnb);
    target_kernel<<<NB / 4, 256, 0, stream>>>(xnb, W, labels, tgt);
    gemm_exp_kernel<<<GRIDSZ, 256, 0, stream>>>(xnb, W, sums);
    finalize_kernel<<<1, 1024, 0, stream>>>(sums, tgt, out);
}